// Round 8
// baseline (372.887 us; speedup 1.0000x reference)
//
#include <hip/hip_runtime.h>

#define T_STEPS 512
#define BATCH   2048
#define HID     64
#define IN0     8
#define SPG     4                 // distinct seqs per group (x4 column replication in N=16)
#define NGRP    2                 // independent recurrence groups per block (intra-wave ILP)
#define SPB     (SPG * NGRP)      // 8 distinct seqs per block
#define NBLK    (BATCH / SPB)     // 256 blocks -> exactly 1 per CU

typedef _Float16 h2 __attribute__((ext_vector_type(2)));
typedef _Float16 h4 __attribute__((ext_vector_type(4)));
typedef _Float16 h8 __attribute__((ext_vector_type(8)));
typedef float    f4 __attribute__((ext_vector_type(4)));

#define MFMA(a, b, c) __builtin_amdgcn_mfma_f32_16x16x32_f16((a), (b), (c), 0, 0, 0)

union F8 { h8 v; h2 p[4]; };
union H4U { h4 v; h2 p[2]; };

__device__ __forceinline__ h2 pkrtz(float a, float b) {
    return __builtin_bit_cast(h2, __builtin_amdgcn_cvt_pkrtz(a, b));
}

// tanh(x) = 1 - 2/(exp(2x)+1); saturates correctly at +/-inf.
__device__ __forceinline__ float tanh_fast(float x) {
    float e = __builtin_amdgcn_exp2f(x * 2.885390081777927f);
    return 1.0f - 2.0f * __builtin_amdgcn_rcpf(e + 1.0f);
}

__global__ __launch_bounds__(256, 1)
void rnn2_mfma(const float* __restrict__ x,
               const float* __restrict__ Wih0, const float* __restrict__ Whh0,
               const float* __restrict__ bih0, const float* __restrict__ bhh0,
               const float* __restrict__ Wih1, const float* __restrict__ Whh1,
               const float* __restrict__ bih1, const float* __restrict__ bhh1,
               const float* __restrict__ fcw,  const float* __restrict__ fcb,
               float* __restrict__ out) {
    const int tid  = threadIdx.x;
    const int w    = tid >> 6;    // wave id = m-tile (H rows 16w..16w+15)
    const int lane = tid & 63;
    const int n    = lane & 15;   // B,C column; sequence = base + (n&3) (4x replicated)
    const int q    = lane >> 4;   // quad: k-block for A/B, row-block for C
    const int m    = n & 3;       // distinct sequence id within group
    const int bseq = blockIdx.x * SPB;

    // Per-group deduped H: 4 rows (seqs) x 64 k, f16, XOR-16-block swizzled:
    // element (row m, k=16B+o) at m*64 + 16*(B^m) + o. Writes conflict-free,
    // reads are 4-lane broadcasts (verified: conflicts = 0 in R7).
    __shared__ __align__(16) _Float16 H0b[NGRP][2][SPG * HID];
    __shared__ __align__(16) _Float16 H1b[NGRP][2][SPG * HID];
    __shared__ float red[NGRP][4][16];

    const int widx  = n * HID + 16 * (w ^ n) + 4 * q;                 // n<4 only
    const int ridx0 = m * HID + 16 * (((q >> 1) + 0) ^ m) + 8 * (q & 1);
    const int ridx1 = m * HID + 16 * (((q >> 1) + 2) ^ m) + 8 * (q & 1);

    // ---- resident A-fragments for rows 16w+n: slot j <-> k = 32kt+8q+j ----
    h8 wh0[2], wi1[2], wh1[2];
    const int row = 16 * w + n;
    #pragma unroll
    for (int kt = 0; kt < 2; ++kt) {
        const int k0 = 32 * kt + 8 * q;
        {
            const float4* p = (const float4*)(Whh0 + row * HID + k0);
            float4 a = p[0], b = p[1];
            F8 f; f.p[0] = pkrtz(a.x, a.y); f.p[1] = pkrtz(a.z, a.w);
                  f.p[2] = pkrtz(b.x, b.y); f.p[3] = pkrtz(b.z, b.w);
            wh0[kt] = f.v;
        }
        {
            const float4* p = (const float4*)(Wih1 + row * HID + k0);
            float4 a = p[0], b = p[1];
            F8 f; f.p[0] = pkrtz(a.x, a.y); f.p[1] = pkrtz(a.z, a.w);
                  f.p[2] = pkrtz(b.x, b.y); f.p[3] = pkrtz(b.z, b.w);
            wi1[kt] = f.v;
        }
        {
            const float4* p = (const float4*)(Whh1 + row * HID + k0);
            float4 a = p[0], b = p[1];
            F8 f; f.p[0] = pkrtz(a.x, a.y); f.p[1] = pkrtz(a.z, a.w);
                  f.p[2] = pkrtz(b.x, b.y); f.p[3] = pkrtz(b.z, b.w);
            wh1[kt] = f.v;
        }
    }
    // Wih0 (64x8), K zero-padded; slot 0 holds k=2q,2q+1 (X B-frag matches)
    const h2 z2 = pkrtz(0.f, 0.f);
    h8 wi0;
    {
        const float2 ww = *(const float2*)(Wih0 + row * IN0 + 2 * q);
        F8 f; f.p[0] = pkrtz(ww.x, ww.y);
        f.p[1] = z2; f.p[2] = z2; f.p[3] = z2;
        wi0 = f.v;
    }
    // biases / fc weights in C-layout: reg r <-> row 16w + 4q + r
    f4 bias0, bias1, fcv;
    #pragma unroll
    for (int r = 0; r < 4; ++r) {
        const int i = 16 * w + 4 * q + r;
        bias0[r] = bih0[i] + bhh0[i];
        bias1[r] = bih1[i] + bhh1[i];
        fcv[r]   = fcw[i];
    }
    const float fcb0 = fcb[0];
    const f4 zero = {0.f, 0.f, 0.f, 0.f};

    // per-group x stream: lane (q,n) reads x[bseq+4g+m][t][2q..2q+1]
    const float* xp[NGRP];
    #pragma unroll
    for (int g = 0; g < NGRP; ++g)
        xp[g] = x + ((size_t)(bseq + SPG * g + m) * T_STEPS) * IN0 + 2 * q;

    h8 h0f[NGRP][2] = {}; h8 h1f[NGRP][2] = {};   // H0_{t-1}, H1_{t-2} (start 0)
    f4 a0x[NGRP];
    #pragma unroll
    for (int g = 0; g < NGRP; ++g) {
        const float2 x0 = *(const float2*)xp[g];
        F8 xf; xf.p[0] = pkrtz(x0.x, x0.y);
        xf.p[1] = z2; xf.p[2] = z2; xf.p[3] = z2;
        a0x[g] = MFMA(wi0, xf.v, bias0);
    }

    #pragma unroll 2
    for (int t = 0; t < T_STEPS; ++t) {
        const int tn = (t + 1 < T_STEPS) ? t + 1 : t;
        const int bf = t & 1;
        float2 xn[NGRP];
        #pragma unroll
        for (int g = 0; g < NGRP; ++g)
            xn[g] = *(const float2*)(xp[g] + tn * IN0);

        // two independent recurrence chains; compiler interleaves their
        // MFMAs/tanh so each fills the other's latency bubbles
        #pragma unroll
        for (int g = 0; g < NGRP; ++g) {
            // layer0(t): a0 = a0x + Whh0@H0_{t-1}
            f4 a0 = MFMA(wh0[0], h0f[g][0], a0x[g]);
            a0    = MFMA(wh0[1], h0f[g][1], a0);
            // layer1(t-1): a1 = b1 + Wih1@H0_{t-1} + Whh1@H1_{t-2}
            f4 c1 = MFMA(wi1[0], h0f[g][0], bias1);
            c1    = MFMA(wi1[1], h0f[g][1], c1);
            f4 c2 = MFMA(wh1[0], h1f[g][0], zero);
            c2    = MFMA(wh1[1], h1f[g][1], c2);

            H4U u0;
            u0.p[0] = pkrtz(tanh_fast(a0[0]), tanh_fast(a0[1]));
            u0.p[1] = pkrtz(tanh_fast(a0[2]), tanh_fast(a0[3]));
            const f4 a1 = c1 + c2;
            H4U u1;
            u1.p[0] = pkrtz(tanh_fast(a1[0]), tanh_fast(a1[1]));
            u1.p[1] = pkrtz(tanh_fast(a1[2]), tanh_fast(a1[3]));
            if (t == 0) { u1.p[0] = z2; u1.p[1] = z2; }   // true H1_{-1}=0 (uniform branch)
            if (n < SPG) {
                *(h4*)&H0b[g][bf][widx] = u0.v;
                *(h4*)&H1b[g][bf][widx] = u1.v;
            }
            // hoisted Wih0@x_{t+1} + bias0 (pre-barrier filler work)
            F8 xf; xf.p[0] = pkrtz(xn[g].x, xn[g].y);
            xf.p[1] = z2; xf.p[2] = z2; xf.p[3] = z2;
            a0x[g] = MFMA(wi0, xf.v, bias0);
        }

        __syncthreads();

        #pragma unroll
        for (int g = 0; g < NGRP; ++g) {
            h0f[g][0] = *(const h8*)&H0b[g][bf][ridx0];
            h0f[g][1] = *(const h8*)&H0b[g][bf][ridx1];
            h1f[g][0] = *(const h8*)&H1b[g][bf][ridx0];
            h1f[g][1] = *(const h8*)&H1b[g][bf][ridx1];
        }
    }

    // ---- epilogue: layer1(T-1) per group, then FC head ----
    #pragma unroll
    for (int g = 0; g < NGRP; ++g) {
        f4 c1 = MFMA(wi1[0], h0f[g][0], bias1);
        c1    = MFMA(wi1[1], h0f[g][1], c1);
        f4 c2 = MFMA(wh1[0], h1f[g][0], zero);
        c2    = MFMA(wh1[1], h1f[g][1], c2);
        const f4 a1 = c1 + c2;
        float s = 0.f;
        #pragma unroll
        for (int r = 0; r < 4; ++r) s += fcv[r] * tanh_fast(a1[r]);
        s += __shfl_xor(s, 16, 64);
        s += __shfl_xor(s, 32, 64);
        if (lane < 16) red[g][w][n] = s;   // q==0 lanes
    }
    __syncthreads();
    if (tid < SPB) {
        const int g = tid >> 2, mm = tid & 3;
        out[bseq + SPG * g + mm] =
            red[g][0][mm] + red[g][1][mm] + red[g][2][mm] + red[g][3][mm] + fcb0;
    }
}

extern "C" void kernel_launch(void* const* d_in, const int* in_sizes, int n_in,
                              void* d_out, int out_size, void* d_ws, size_t ws_size,
                              hipStream_t stream) {
    const float* x    = (const float*)d_in[0];
    const float* Wih0 = (const float*)d_in[1];
    const float* Whh0 = (const float*)d_in[2];
    const float* bih0 = (const float*)d_in[3];
    const float* bhh0 = (const float*)d_in[4];
    const float* Wih1 = (const float*)d_in[5];
    const float* Whh1 = (const float*)d_in[6];
    const float* bih1 = (const float*)d_in[7];
    const float* bhh1 = (const float*)d_in[8];
    const float* fcw  = (const float*)d_in[9];
    const float* fcb  = (const float*)d_in[10];
    float* out = (float*)d_out;

    rnn2_mfma<<<dim3(NBLK), dim3(256), 0, stream>>>(
        x, Wih0, Whh0, bih0, bhh0, Wih1, Whh1, bih1, bhh1, fcw, fcb, out);
}

// Round 9
// 346.292 us; speedup vs baseline: 1.0768x; 1.0768x over previous
//
#include <hip/hip_runtime.h>

#define T_STEPS 512
#define BATCH   2048
#define HID     64
#define IN0     8
#define SPG     4                 // distinct seqs per block (x4 column replication in N=16)
#define NBLK    (BATCH / SPG)     // 512 blocks x 2 waves -> 2 blocks/CU, 1 wave/SIMD
#define SS      8                 // steps per superstep (barrier amortization)
#define NSS     (T_STEPS / SS)    // 64
#define RSLOTS  16                // H0 ring slots (2 supersteps)

typedef _Float16 h2 __attribute__((ext_vector_type(2)));
typedef _Float16 h4 __attribute__((ext_vector_type(4)));
typedef _Float16 h8 __attribute__((ext_vector_type(8)));
typedef float    f4 __attribute__((ext_vector_type(4)));

#define MFMA(a, b, c) __builtin_amdgcn_mfma_f32_16x16x32_f16((a), (b), (c), 0, 0, 0)

union F8 { h8 v; h2 p[4]; };
union H4U { h4 v; h2 p[2]; };

__device__ __forceinline__ h2 pkrtz(float a, float b) {
    return __builtin_bit_cast(h2, __builtin_amdgcn_cvt_pkrtz(a, b));
}

// tanh(x) = 1 - 2/(exp(2x)+1); saturates correctly at +/-inf.
__device__ __forceinline__ float tanh_fast(float x) {
    float e = __builtin_amdgcn_exp2f(x * 2.885390081777927f);
    return 1.0f - 2.0f * __builtin_amdgcn_rcpf(e + 1.0f);
}

__device__ __forceinline__ h8 load_frag_f16(const float* Wrow) {
    const float4* p = (const float4*)Wrow;
    float4 a = p[0], b = p[1];
    F8 f; f.p[0] = pkrtz(a.x, a.y); f.p[1] = pkrtz(a.z, a.w);
          f.p[2] = pkrtz(b.x, b.y); f.p[3] = pkrtz(b.z, b.w);
    return f.v;
}

__global__ __launch_bounds__(128, 1)
void rnn2_pipe(const float* __restrict__ x,
               const float* __restrict__ Wih0, const float* __restrict__ Whh0,
               const float* __restrict__ bih0, const float* __restrict__ bhh0,
               const float* __restrict__ Wih1, const float* __restrict__ Whh1,
               const float* __restrict__ bih1, const float* __restrict__ bhh1,
               const float* __restrict__ fcw,  const float* __restrict__ fcb,
               float* __restrict__ out) {
    const int tid  = threadIdx.x;
    const int w    = tid >> 6;    // wave 0 = layer0 producer, wave 1 = layer1 consumer
    const int lane = tid & 63;
    const int n    = lane & 15;   // B/C column; seq = bseq + (n&3)
    const int q    = lane >> 4;
    const int m    = n & 3;
    const int bseq = blockIdx.x * SPG;

    // H0 ring (16 steps) + H1 double buffer; XOR-16-block swizzle
    // (row m, k=16B+o) -> m*64 + 16*(B^m) + o. Verified conflict-free (R7).
    __shared__ __align__(16) _Float16 ring[RSLOTS][SPG * HID];
    __shared__ __align__(16) _Float16 h1b[2][SPG * HID];

    const int widxb = n * HID + 4 * q;   // + 16*(mt^n), lanes n<4 only
    const int ridx0 = m * HID + 16 * (((q >> 1) + 0) ^ m) + 8 * (q & 1);
    const int ridx1 = m * HID + 16 * (((q >> 1) + 2) ^ m) + 8 * (q & 1);

    const f4 zero = {0.f, 0.f, 0.f, 0.f};
    const h2 z2 = pkrtz(0.f, 0.f);

    // ---------- per-wave persistent state (init under wave guard) ----------
    h8 wh0[4][2], wi0[4];  f4 bias0c[4];          // wave0
    h8 wi1[4][2], wh1[4][2]; f4 bias1c[4];        // wave1
    h8 h0f[2] = {}, h1f[2] = {};
    f4 a0x[4];
    const float* xrow = x + ((size_t)(bseq + m) * T_STEPS) * IN0 + 2 * q;

    if (w == 0) {
        #pragma unroll
        for (int mt = 0; mt < 4; ++mt) {
            const int row = 16 * mt + n;
            #pragma unroll
            for (int kt = 0; kt < 2; ++kt)
                wh0[mt][kt] = load_frag_f16(Whh0 + row * HID + 32 * kt + 8 * q);
            const float2 ww = *(const float2*)(Wih0 + row * IN0 + 2 * q);
            F8 f; f.p[0] = pkrtz(ww.x, ww.y); f.p[1] = z2; f.p[2] = z2; f.p[3] = z2;
            wi0[mt] = f.v;
            #pragma unroll
            for (int r = 0; r < 4; ++r) {
                const int i = 16 * mt + 4 * q + r;
                bias0c[mt][r] = bih0[i] + bhh0[i];
            }
        }
        // a0x(0) = bias0 + Wih0 @ x(0)
        const float2 x0 = *(const float2*)xrow;
        F8 xf; xf.p[0] = pkrtz(x0.x, x0.y); xf.p[1] = z2; xf.p[2] = z2; xf.p[3] = z2;
        #pragma unroll
        for (int mt = 0; mt < 4; ++mt) a0x[mt] = MFMA(wi0[mt], xf.v, bias0c[mt]);
    } else {
        #pragma unroll
        for (int mt = 0; mt < 4; ++mt) {
            const int row = 16 * mt + n;
            #pragma unroll
            for (int kt = 0; kt < 2; ++kt) {
                wi1[mt][kt] = load_frag_f16(Wih1 + row * HID + 32 * kt + 8 * q);
                wh1[mt][kt] = load_frag_f16(Whh1 + row * HID + 32 * kt + 8 * q);
            }
            #pragma unroll
            for (int r = 0; r < 4; ++r) {
                const int i = 16 * mt + 4 * q + r;
                bias1c[mt][r] = bih1[i] + bhh1[i];
            }
        }
    }

    // ---------- superstep pipeline: wave0 at s, wave1 at s-1 ----------
    for (int s = 0; s <= NSS; ++s) {
        if (w == 0) {
            if (s < NSS) {
                const int t0 = SS * s;
                // prefetch x(t0+1 .. t0+8)
                float2 xb[SS];
                #pragma unroll
                for (int i = 0; i < SS; ++i) {
                    int tn = t0 + i + 1; if (tn > T_STEPS - 1) tn = T_STEPS - 1;
                    xb[i] = *(const float2*)(xrow + tn * IN0);
                }
                #pragma unroll
                for (int i = 0; i < SS; ++i) {
                    const int t = t0 + i;
                    f4 a0[4];
                    #pragma unroll
                    for (int mt = 0; mt < 4; ++mt) {
                        a0[mt] = MFMA(wh0[mt][0], h0f[0], a0x[mt]);
                        a0[mt] = MFMA(wh0[mt][1], h0f[1], a0[mt]);
                    }
                    _Float16* slot = ring[t & (RSLOTS - 1)];
                    #pragma unroll
                    for (int mt = 0; mt < 4; ++mt) {
                        H4U u;
                        u.p[0] = pkrtz(tanh_fast(a0[mt][0]), tanh_fast(a0[mt][1]));
                        u.p[1] = pkrtz(tanh_fast(a0[mt][2]), tanh_fast(a0[mt][3]));
                        if (n < SPG) *(h4*)&slot[widxb + 16 * (mt ^ n)] = u.v;
                    }
                    // a0x(t+1) — off the critical path
                    F8 xf; xf.p[0] = pkrtz(xb[i].x, xb[i].y);
                    xf.p[1] = z2; xf.p[2] = z2; xf.p[3] = z2;
                    #pragma unroll
                    for (int mt = 0; mt < 4; ++mt)
                        a0x[mt] = MFMA(wi0[mt], xf.v, bias0c[mt]);
                    __builtin_amdgcn_wave_barrier();
                    h0f[0] = *(const h8*)&slot[ridx0];
                    h0f[1] = *(const h8*)&slot[ridx1];
                }
            }
        } else {
            if (s > 0) {
                const int t0 = SS * (s - 1);
                #pragma unroll
                for (int i = 0; i < SS; ++i) {
                    const int t = t0 + i;
                    const _Float16* slot = ring[t & (RSLOTS - 1)];
                    const h8 h0r0 = *(const h8*)&slot[ridx0];
                    const h8 h0r1 = *(const h8*)&slot[ridx1];
                    f4 c1[4], c2[4];
                    #pragma unroll
                    for (int mt = 0; mt < 4; ++mt) {
                        c1[mt] = MFMA(wi1[mt][0], h0r0, bias1c[mt]);
                        c1[mt] = MFMA(wi1[mt][1], h0r1, c1[mt]);
                        c2[mt] = MFMA(wh1[mt][0], h1f[0], zero);
                        c2[mt] = MFMA(wh1[mt][1], h1f[1], c2[mt]);
                    }
                    _Float16* s1 = h1b[t & 1];
                    #pragma unroll
                    for (int mt = 0; mt < 4; ++mt) {
                        const f4 a1 = c1[mt] + c2[mt];
                        H4U u;
                        u.p[0] = pkrtz(tanh_fast(a1[0]), tanh_fast(a1[1]));
                        u.p[1] = pkrtz(tanh_fast(a1[2]), tanh_fast(a1[3]));
                        if (n < SPG) *(h4*)&s1[widxb + 16 * (mt ^ n)] = u.v;
                    }
                    __builtin_amdgcn_wave_barrier();
                    h1f[0] = *(const h8*)&s1[ridx0];
                    h1f[1] = *(const h8*)&s1[ridx1];
                }
            }
        }
        __syncthreads();
    }

    // ---------- FC head (wave1 holds H1(511) in h1f) ----------
    if (w == 1) {
        float s = 0.f;
        #pragma unroll
        for (int kt = 0; kt < 2; ++kt)
            #pragma unroll
            for (int j = 0; j < 8; ++j)
                s += fcw[32 * kt + 8 * q + j] * (float)h1f[kt][j];
        s += __shfl_xor(s, 16, 64);
        s += __shfl_xor(s, 32, 64);
        if (lane < SPG) out[bseq + lane] = s + fcb[0];
    }
}

extern "C" void kernel_launch(void* const* d_in, const int* in_sizes, int n_in,
                              void* d_out, int out_size, void* d_ws, size_t ws_size,
                              hipStream_t stream) {
    const float* x    = (const float*)d_in[0];
    const float* Wih0 = (const float*)d_in[1];
    const float* Whh0 = (const float*)d_in[2];
    const float* bih0 = (const float*)d_in[3];
    const float* bhh0 = (const float*)d_in[4];
    const float* Wih1 = (const float*)d_in[5];
    const float* Whh1 = (const float*)d_in[6];
    const float* bih1 = (const float*)d_in[7];
    const float* bhh1 = (const float*)d_in[8];
    const float* fcw  = (const float*)d_in[9];
    const float* fcb  = (const float*)d_in[10];
    float* out = (float*)d_out;

    rnn2_pipe<<<dim3(NBLK), dim3(128), 0, stream>>>(
        x, Wih0, Whh0, bih0, bhh0, Wih1, Whh1, bih1, bhh1, fcw, fcb, out);
}

// Round 10
// 239.945 us; speedup vs baseline: 1.5541x; 1.4432x over previous
//
#include <hip/hip_runtime.h>

#define T_STEPS 512
#define BATCH   2048
#define HID     64
#define IN0     8
#define SPW     16                // distinct seqs per block (MFMA N dim)
#define NBLK    (BATCH / SPW)     // 128 blocks x 8 waves (512 thr)
#define SS      8                 // x-prefetch depth
#define NSS     (T_STEPS / SS)

typedef _Float16 h2 __attribute__((ext_vector_type(2)));
typedef _Float16 h4 __attribute__((ext_vector_type(4)));
typedef _Float16 h8 __attribute__((ext_vector_type(8)));
typedef float    f4 __attribute__((ext_vector_type(4)));

#define MFMA(a, b, c) __builtin_amdgcn_mfma_f32_16x16x32_f16((a), (b), (c), 0, 0, 0)

union F8 { h8 v; h2 p[4]; };
union H4U { h4 v; h2 p[2]; };

__device__ __forceinline__ h2 pkrtz(float a, float b) {
    return __builtin_bit_cast(h2, __builtin_amdgcn_cvt_pkrtz(a, b));
}

// tanh(x) = 1 - 2/(exp(2x)+1); saturates correctly at +/-inf.
__device__ __forceinline__ float tanh_fast(float x) {
    float e = __builtin_amdgcn_exp2f(x * 2.885390081777927f);
    return 1.0f - 2.0f * __builtin_amdgcn_rcpf(e + 1.0f);
}

__device__ __forceinline__ h8 load_frag_f16(const float* Wrow) {
    const float4* p = (const float4*)Wrow;
    float4 a = p[0], b = p[1];
    F8 f; f.p[0] = pkrtz(a.x, a.y); f.p[1] = pkrtz(a.z, a.w);
          f.p[2] = pkrtz(b.x, b.y); f.p[3] = pkrtz(b.z, b.w);
    return f.v;
}

__global__ __launch_bounds__(512, 1)
void rnn2_split(const float* __restrict__ x,
                const float* __restrict__ Wih0, const float* __restrict__ Whh0,
                const float* __restrict__ bih0, const float* __restrict__ bhh0,
                const float* __restrict__ Wih1, const float* __restrict__ Whh1,
                const float* __restrict__ bih1, const float* __restrict__ bhh1,
                const float* __restrict__ fcw,  const float* __restrict__ fcb,
                float* __restrict__ out) {
    const int tid  = threadIdx.x;
    const int w    = tid >> 6;
    const int mt   = w & 3;        // m-tile (H rows 16mt..16mt+15)
    const bool L0  = (w < 4);      // waves 0-3: layer0; waves 4-7: layer1
    const int lane = tid & 63;
    const int n    = lane & 15;    // B/C column = sequence (16 distinct)
    const int q    = lane >> 4;
    const int bseq = blockIdx.x * SPW;

    // H buffers [n][k], k-stride 72 (+8 pad, 0 conflicts verified R5);
    // double-buffered by t&1. Phase t publishes H0(t), H1(t-1).
    __shared__ __align__(16) _Float16 H0b[2][SPW * 72];
    __shared__ __align__(16) _Float16 H1b[2][SPW * 72];
    __shared__ float red[4][SPW];

    const int widx  = n * 72 + mt * 16 + q * 4;   // this wave's C rows: k=16mt+4q+r
    const int ridx0 = n * 72 + 0 * 32 + q * 8;    // B-frag slices
    const int ridx1 = n * 72 + 1 * 32 + q * 8;

    const f4 zero = {0.f, 0.f, 0.f, 0.f};
    const h2 z2 = pkrtz(0.f, 0.f);

    // ---- per-role weight fragments (slot j <-> k = 32kt+8q+j) ----
    h8 wa[2], wb[2], wi0;          // L0: wa=Whh0 | L1: wa=Wih1, wb=Whh1
    f4 biasc, fcv;
    const int row = 16 * mt + n;
    if (L0) {
        #pragma unroll
        for (int kt = 0; kt < 2; ++kt)
            wa[kt] = load_frag_f16(Whh0 + row * HID + 32 * kt + 8 * q);
        const float2 ww = *(const float2*)(Wih0 + row * IN0 + 2 * q);
        F8 f; f.p[0] = pkrtz(ww.x, ww.y); f.p[1] = z2; f.p[2] = z2; f.p[3] = z2;
        wi0 = f.v;
        #pragma unroll
        for (int r = 0; r < 4; ++r) {
            const int i = 16 * mt + 4 * q + r;
            biasc[r] = bih0[i] + bhh0[i];
        }
    } else {
        #pragma unroll
        for (int kt = 0; kt < 2; ++kt) {
            wa[kt] = load_frag_f16(Wih1 + row * HID + 32 * kt + 8 * q);
            wb[kt] = load_frag_f16(Whh1 + row * HID + 32 * kt + 8 * q);
        }
        #pragma unroll
        for (int r = 0; r < 4; ++r) {
            const int i = 16 * mt + 4 * q + r;
            biasc[r] = bih1[i] + bhh1[i];
            fcv[r]   = fcw[i];
        }
    }
    const float fcb0 = fcb[0];

    const float* xrow = x + ((size_t)(bseq + n) * T_STEPS) * IN0 + 2 * q;

    h8 h0f[2] = {}, h1f[2] = {};   // H0(t-1); (L1 only) H1(t-2)
    f4 a0x;                        // L0: bias0 + Wih0@x(t)
    if (L0) {
        const float2 x0 = *(const float2*)xrow;
        F8 xf; xf.p[0] = pkrtz(x0.x, x0.y); xf.p[1] = z2; xf.p[2] = z2; xf.p[3] = z2;
        a0x = MFMA(wi0, xf.v, biasc);
    }

    for (int s = 0; s < NSS; ++s) {
        float2 xb[SS];
        if (L0) {
            #pragma unroll
            for (int i = 0; i < SS; ++i) {
                int tn = SS * s + i + 1; if (tn > T_STEPS - 1) tn = T_STEPS - 1;
                xb[i] = *(const float2*)(xrow + tn * IN0);
            }
        }
        #pragma unroll
        for (int i = 0; i < SS; ++i) {
            const int t = SS * s + i;
            const int bf = t & 1;
            if (L0) {
                // H0(t) = tanh(a0x + Whh0@H0(t-1))
                f4 a0 = MFMA(wa[0], h0f[0], a0x);
                a0    = MFMA(wa[1], h0f[1], a0);
                H4U u;
                u.p[0] = pkrtz(tanh_fast(a0[0]), tanh_fast(a0[1]));
                u.p[1] = pkrtz(tanh_fast(a0[2]), tanh_fast(a0[3]));
                *(h4*)&H0b[bf][widx] = u.v;
                // a0x(t+1) — off the chain
                F8 xf; xf.p[0] = pkrtz(xb[i].x, xb[i].y);
                xf.p[1] = z2; xf.p[2] = z2; xf.p[3] = z2;
                a0x = MFMA(wi0, xf.v, biasc);
            } else {
                // H1(t-1) = tanh(b1 + Wih1@H0(t-1) + Whh1@H1(t-2))
                f4 c1 = MFMA(wa[0], h0f[0], biasc);
                c1    = MFMA(wa[1], h0f[1], c1);
                f4 c2 = MFMA(wb[0], h1f[0], zero);
                c2    = MFMA(wb[1], h1f[1], c2);
                const f4 a1 = c1 + c2;
                H4U u;
                u.p[0] = pkrtz(tanh_fast(a1[0]), tanh_fast(a1[1]));
                u.p[1] = pkrtz(tanh_fast(a1[2]), tanh_fast(a1[3]));
                if (t == 0) { u.p[0] = z2; u.p[1] = z2; }   // true H1(-1)=0
                *(h4*)&H1b[bf][widx] = u.v;
            }
            __syncthreads();
            h0f[0] = *(const h8*)&H0b[bf][ridx0];
            h0f[1] = *(const h8*)&H0b[bf][ridx1];
            if (!L0) {
                h1f[0] = *(const h8*)&H1b[bf][ridx0];
                h1f[1] = *(const h8*)&H1b[bf][ridx1];
            }
        }
    }

    // ---- epilogue: H1(511) from h0f=H0(511), h1f=H1(510); FC head ----
    if (!L0) {
        f4 c1 = MFMA(wa[0], h0f[0], biasc);
        c1    = MFMA(wa[1], h0f[1], c1);
        f4 c2 = MFMA(wb[0], h1f[0], zero);
        c2    = MFMA(wb[1], h1f[1], c2);
        const f4 a1 = c1 + c2;
        float sacc = 0.f;
        #pragma unroll
        for (int r = 0; r < 4; ++r) sacc += fcv[r] * tanh_fast(a1[r]);
        sacc += __shfl_xor(sacc, 16, 64);
        sacc += __shfl_xor(sacc, 32, 64);
        if (lane < 16) red[mt][n] = sacc;    // q==0 lanes
    }
    __syncthreads();
    if (tid < SPW)
        out[bseq + tid] = red[0][tid] + red[1][tid] + red[2][tid] + red[3][tid] + fcb0;
}

extern "C" void kernel_launch(void* const* d_in, const int* in_sizes, int n_in,
                              void* d_out, int out_size, void* d_ws, size_t ws_size,
                              hipStream_t stream) {
    const float* x    = (const float*)d_in[0];
    const float* Wih0 = (const float*)d_in[1];
    const float* Whh0 = (const float*)d_in[2];
    const float* bih0 = (const float*)d_in[3];
    const float* bhh0 = (const float*)d_in[4];
    const float* Wih1 = (const float*)d_in[5];
    const float* Whh1 = (const float*)d_in[6];
    const float* bih1 = (const float*)d_in[7];
    const float* bhh1 = (const float*)d_in[8];
    const float* fcw  = (const float*)d_in[9];
    const float* fcb  = (const float*)d_in[10];
    float* out = (float*)d_out;

    rnn2_split<<<dim3(NBLK), dim3(512), 0, stream>>>(
        x, Wih0, Whh0, bih0, bhh0, Wih1, Whh1, bih1, bhh1, fcw, fcb, out);
}